// Round 7
// baseline (98.030 us; speedup 1.0000x reference)
//
#include <hip/hip_runtime.h>
#include <hip/hip_bf16.h>

namespace {

constexpr int MM = 64;
constexpr int KK = 4096;
constexpr int NN = 11008;
constexpr int NZROW = NN / 8;      // 1376
constexpr int BN = 128;            // cols per block tile
constexpr int KSPLIT = 8;
constexpr int KSEG = KK / KSPLIT;  // 512
constexpr int NTILES = NN / BN;    // 86
constexpr int SCK = 128;           // superchunk k-extent == quant group
constexpr int NSC = KSEG / SCK;    // 4 superchunks per block
constexpr int AROW = 68;           // A LDS row stride in ints (64 data + 4 pad; 16B-aligned rows)
constexpr int ABUF = MM * AROW;    // 4352 ints = 17408 B per buffer
constexpr size_t WS_NEED = (size_t)KSPLIT * MM * NN * 4;  // 22.5 MB partials

typedef float f32x4 __attribute__((ext_vector_type(4)));
typedef short s16x8 __attribute__((ext_vector_type(8)));
typedef int   i32x4 __attribute__((ext_vector_type(4)));

// result bf16x2 = (hi16(even), hi16(odd)) — truncating bf16 pack, 1 instr
__device__ __forceinline__ int perm_trunc(float even, float odd) {
  return (int)__builtin_amdgcn_perm(__float_as_uint(odd), __float_as_uint(even), 0x07060302u);
}
// RNE adjust: add 0x7FFF + lsb-of-hi16, then truncate
__device__ __forceinline__ unsigned rne_adj(float f) {
  unsigned u = __float_as_uint(f);
  return u + 0x7FFFu + ((u >> 16) & 1u);
}
__device__ __forceinline__ int pack_rne(float even, float odd) {
  return (int)__builtin_amdgcn_perm(rne_adj(odd), rne_adj(even), 0x07060302u);
}

// fallback path only: out[m][n] = bias[n], atomics on top
__global__ __launch_bounds__(256) void prep_kernel(
    const float* __restrict__ bias, float* __restrict__ out)
{
  const int i = blockIdx.x * 256 + threadIdx.x;
  out[i] = bias[i % NN];
}

// ws path: out = bias + sum of KSPLIT partials
__global__ __launch_bounds__(256) void reduce_kernel(
    const float* __restrict__ ws, const float* __restrict__ bias,
    float* __restrict__ out)
{
  const int i4 = (blockIdx.x * 256 + threadIdx.x) * 4;
  f32x4 acc = *(const f32x4*)(bias + (i4 % NN));
  #pragma unroll
  for (int s = 0; s < KSPLIT; ++s)
    acc += *(const f32x4*)(ws + (size_t)s * (MM * NN) + i4);
  *(f32x4*)(out + i4) = acc;
}

// R7 structure: B (weights) never touch LDS — one qw dword IS a B-fragment's
// per-lane payload (8 nibbles = k=quad*8..+7 at one column). Each wave owns a
// 32-col n-slice and computes 64m x 32n (4 m-tiles x 2 n-tiles = 8 MFMAs per
// 32-k chunk). Only A (x->bf16) is staged in LDS, once per 128-k superchunk
// (= quant group), double-buffered: ONE barrier per superchunk. x + qw for
// SC s+1 issue at SC s start -> ~1 SC of latency cover, per-dependency vmcnt.
template<bool ATOMIC>
__global__ __launch_bounds__(256, 3) void gptq_gemm_kernel(
    const float* __restrict__ x, const int* __restrict__ qw,
    const int* __restrict__ qz, const float* __restrict__ scales,
    float* __restrict__ out)
{
  __shared__ int Albuf[2 * ABUF];   // 34.8 KB

  const int tid  = threadIdx.x;
  const int wave = tid >> 6;
  const int lane = tid & 63;
  const int c    = lane & 15;
  const int quad = lane >> 4;

  const int ks    = blockIdx.x & 7;
  const int ntile = blockIdx.x >> 3;
  const int n0    = ntile * BN;
  const int kbase = ks * KSEG;

  // A staging coords: thread -> (row sm, k-quarter skq) of the 64x128 tile
  const int sm  = tid >> 2;
  const int skq = tid & 3;
  const float* xs = x + sm * KK + kbase + skq * 32;

  // B coords: wave owns n-slice [n0+wave*32, +32)
  const int nb0   = n0 + wave * 32;
  const int ncol0 = nb0 + c;          // u=0 tile column
  const int ncol1 = nb0 + 16 + c;     // u=1 tile column
  const int* qwl  = qw + (size_t)quad * NN + ncol0;
  const int g0    = ks * NSC;

  f32x4 acc[8];
  #pragma unroll
  for (int i = 0; i < 8; ++i) acc[i] = {0.f, 0.f, 0.f, 0.f};

  f32x4 xv[8];        // x in flight for next superchunk (32 floats)
  int   qv[4][2];     // qw dwords in flight (8)
  float ps0[2], ps1[2];
  int   pz0[2], pz1[2];

  auto stage = [&](int sl) {   // pack xv -> Albuf[sl] (RNE bf16)
    int* Ab = Albuf + sl * ABUF;
    int iw[16];
    #pragma unroll
    for (int j = 0; j < 8; ++j) {
      iw[2 * j]     = pack_rne(xv[j].x, xv[j].y);
      iw[2 * j + 1] = pack_rne(xv[j].z, xv[j].w);
    }
    #pragma unroll
    for (int gq = 0; gq < 4; ++gq)
      *(i32x4*)&Ab[sm * AROW + skq * 16 + gq * 4] = *(const i32x4*)&iw[gq * 4];
  };

  // ---- prologue: SC0 loads + stage buf0 ----
  #pragma unroll
  for (int j = 0; j < 8; ++j) xv[j] = *(const f32x4*)(xs + j * 4);
  #pragma unroll
  for (int ch = 0; ch < 4; ++ch) {
    const size_t ro = (size_t)(ks * 64 + ch * 4) * NN;
    qv[ch][0] = qwl[ro];
    qv[ch][1] = qwl[ro + 16];
  }
  ps0[0] = scales[(size_t)g0 * NN + ncol0];
  ps1[0] = scales[(size_t)g0 * NN + ncol1];
  pz0[0] = qz[(size_t)g0 * NZROW + (ncol0 >> 3)];
  pz1[0] = qz[(size_t)g0 * NZROW + (ncol1 >> 3)];
  stage(0);
  __asm__ volatile("s_waitcnt lgkmcnt(0)\n\ts_barrier" ::: "memory");

  #pragma unroll
  for (int s = 0; s < NSC; ++s) {
    const int sl = s & 1;
    // prefetch x / scales / zeros for SC s+1 (xv regs were freed by stage())
    if (s + 1 < NSC) {
      #pragma unroll
      for (int j = 0; j < 8; ++j) xv[j] = *(const f32x4*)(xs + (s + 1) * SCK + j * 4);
      const int g1 = g0 + s + 1;
      ps0[(s + 1) & 1] = scales[(size_t)g1 * NN + ncol0];
      ps1[(s + 1) & 1] = scales[(size_t)g1 * NN + ncol1];
      pz0[(s + 1) & 1] = qz[(size_t)g1 * NZROW + (ncol0 >> 3)];
      pz1[(s + 1) & 1] = qz[(size_t)g1 * NZROW + (ncol1 >> 3)];
    }
    const float s0v = ps0[sl], s1v = ps1[sl];
    const float C0 = (float)(0x800000 + ((pz0[sl] >> ((ncol0 & 7) * 4)) & 15) + 1);
    const float C1 = (float)(0x800000 + ((pz1[sl] >> ((ncol1 & 7) * 4)) & 15) + 1);
    const int* Ab = Albuf + sl * ABUF;

    #pragma unroll
    for (int ch = 0; ch < 4; ++ch) {
      const int v0 = qv[ch][0], v1 = qv[ch][1];
      if (s + 1 < NSC) {   // reload this slot for next SC right after consuming
        const size_t ro = (size_t)(ks * 64 + (s + 1) * 16 + ch * 4) * NN;
        qv[ch][0] = qwl[ro];
        qv[ch][1] = qwl[ro + 16];
      }
      // in-register dequant: qf=(nib|0x4B000000)=2^23+q exact; d=qf-C exact
      // int q-z-1; w=s*d; truncating bf16 pack (1 perm per pair)
      i32x4 b0, b1;
      {
        const float w0 = s0v * (__int_as_float(((v0      ) & 15) | 0x4B000000) - C0);
        const float w1 = s0v * (__int_as_float(((v0 >>  4) & 15) | 0x4B000000) - C0);
        const float w2 = s0v * (__int_as_float(((v0 >>  8) & 15) | 0x4B000000) - C0);
        const float w3 = s0v * (__int_as_float(((v0 >> 12) & 15) | 0x4B000000) - C0);
        const float w4 = s0v * (__int_as_float(((v0 >> 16) & 15) | 0x4B000000) - C0);
        const float w5 = s0v * (__int_as_float(((v0 >> 20) & 15) | 0x4B000000) - C0);
        const float w6 = s0v * (__int_as_float(((v0 >> 24) & 15) | 0x4B000000) - C0);
        const float w7 = s0v * (__int_as_float(((v0 >> 28) & 15) | 0x4B000000) - C0);
        b0.x = perm_trunc(w0, w1); b0.y = perm_trunc(w2, w3);
        b0.z = perm_trunc(w4, w5); b0.w = perm_trunc(w6, w7);
      }
      {
        const float w0 = s1v * (__int_as_float(((v1      ) & 15) | 0x4B000000) - C1);
        const float w1 = s1v * (__int_as_float(((v1 >>  4) & 15) | 0x4B000000) - C1);
        const float w2 = s1v * (__int_as_float(((v1 >>  8) & 15) | 0x4B000000) - C1);
        const float w3 = s1v * (__int_as_float(((v1 >> 12) & 15) | 0x4B000000) - C1);
        const float w4 = s1v * (__int_as_float(((v1 >> 16) & 15) | 0x4B000000) - C1);
        const float w5 = s1v * (__int_as_float(((v1 >> 20) & 15) | 0x4B000000) - C1);
        const float w6 = s1v * (__int_as_float(((v1 >> 24) & 15) | 0x4B000000) - C1);
        const float w7 = s1v * (__int_as_float(((v1 >> 28) & 15) | 0x4B000000) - C1);
        b1.x = perm_trunc(w0, w1); b1.y = perm_trunc(w2, w3);
        b1.z = perm_trunc(w4, w5); b1.w = perm_trunc(w6, w7);
      }
      const s16x8 bf0 = __builtin_bit_cast(s16x8, b0);
      const s16x8 bf1 = __builtin_bit_cast(s16x8, b1);

      #pragma unroll
      for (int t = 0; t < 4; ++t) {
        const s16x8 af = *(const s16x8*)&Ab[(16 * t + c) * AROW + ch * 16 + quad * 4];
        acc[2 * t]     = __builtin_amdgcn_mfma_f32_16x16x32_bf16(af, bf0, acc[2 * t],     0, 0, 0);
        acc[2 * t + 1] = __builtin_amdgcn_mfma_f32_16x16x32_bf16(af, bf1, acc[2 * t + 1], 0, 0, 0);
      }
    }

    if (s + 1 < NSC) {
      stage((s + 1) & 1);
      __asm__ volatile("s_waitcnt lgkmcnt(0)\n\ts_barrier" ::: "memory");
    }
  }

  // ---- epilogue: wave writes its 64m x 32n tile ----
  if (ATOMIC) {
    #pragma unroll
    for (int t = 0; t < 4; ++t)
      #pragma unroll
      for (int u = 0; u < 2; ++u) {
        const int N = nb0 + u * 16 + c;
        const f32x4 a = acc[2 * t + u];
        const int m0 = 16 * t + quad * 4;
        atomicAdd(&out[(m0 + 0) * NN + N], a.x);
        atomicAdd(&out[(m0 + 1) * NN + N], a.y);
        atomicAdd(&out[(m0 + 2) * NN + N], a.z);
        atomicAdd(&out[(m0 + 3) * NN + N], a.w);
      }
  } else {
    float* wsp = out + (size_t)ks * (MM * NN);
    #pragma unroll
    for (int t = 0; t < 4; ++t)
      #pragma unroll
      for (int u = 0; u < 2; ++u) {
        const int N = nb0 + u * 16 + c;
        const f32x4 a = acc[2 * t + u];
        const int m0 = 16 * t + quad * 4;
        wsp[(m0 + 0) * NN + N] = a.x;
        wsp[(m0 + 1) * NN + N] = a.y;
        wsp[(m0 + 2) * NN + N] = a.z;
        wsp[(m0 + 3) * NN + N] = a.w;
      }
  }
}

} // namespace

extern "C" void kernel_launch(void* const* d_in, const int* in_sizes, int n_in,
                              void* d_out, int out_size, void* d_ws, size_t ws_size,
                              hipStream_t stream) {
  const float* x      = (const float*)d_in[0];
  const int*   qw     = (const int*)d_in[1];
  const int*   qz     = (const int*)d_in[2];
  const float* scales = (const float*)d_in[3];
  const float* bias   = (const float*)d_in[4];
  float* out = (float*)d_out;

  if (ws_size >= WS_NEED) {
    float* ws = (float*)d_ws;
    gptq_gemm_kernel<false><<<NTILES * KSPLIT, 256, 0, stream>>>(x, qw, qz, scales, ws);
    reduce_kernel<<<(MM * NN) / 1024, 256, 0, stream>>>(ws, bias, out);
  } else {
    prep_kernel<<<(MM * NN) / 256, 256, 0, stream>>>(bias, out);
    gptq_gemm_kernel<true><<<NTILES * KSPLIT, 256, 0, stream>>>(x, qw, qz, scales, out);
  }
}